// Round 13
// baseline (311.441 us; speedup 1.0000x reference)
//
#include <hip/hip_runtime.h>
#include <hip/hip_bf16.h>
#include <cstdint>

typedef __attribute__((ext_vector_type(8))) short short8;
typedef __attribute__((ext_vector_type(4))) float f32x4;

#define DEV static __device__ __forceinline__

DEV float b2f(unsigned short u) {
  union { unsigned int i; float f; } c; c.i = ((unsigned int)u) << 16; return c.f;
}
DEV unsigned short f2b(float f) {
  __hip_bfloat16 h = __float2bfloat16(f);          // HW cvt, RNE
  return *reinterpret_cast<unsigned short*>(&h);
}

DEV void async16(const void* g, void* l) {
  __builtin_amdgcn_global_load_lds((__attribute__((address_space(1))) void*)g,
                                   (__attribute__((address_space(3))) void*)l, 16, 0, 0);
}

union U8 { uint4 v; unsigned short s[8]; };

// ================= fast path: bf16 GEMM, global_load_lds + counted-vmcnt (clean) ======
// C[M,N] = scale * A @ Bt^T + bias.  A [M,K] bf16 row-major, Bt [N,K] bf16 row-major.
// 3-buffer distance-2 prefetch, s_waitcnt vmcnt(4) (tile kt+1 ready, kt+2 in flight).
// vs round-11: NO sched_barrier(0), offsets via SGPR rotation (no ternaries).
// + T1 XCD chunked swizzle (nwg % 8 == 0 at all call sites).
template<int BIAS, int RELU, int OF32, int SCALED, int CSKIP, int CKLIM>
__global__ __launch_bounds__(256) void gemm_gll(
    const unsigned short* __restrict__ A, const unsigned short* __restrict__ Bt,
    const float* __restrict__ bias, void* __restrict__ outv,
    int K, int lda, int ldb, int ldc,
    long long bsA, long long bsB, long long bsC, float scale)
{
  // --- XCD swizzle: each XCD gets a contiguous chunk of the linearized grid ---
  int bx = blockIdx.x, by = blockIdx.y, bz = blockIdx.z;
  {
    const int gx = gridDim.x, gy = gridDim.y;
    const int nwg = gx * gy * gridDim.z;          // divisible by 8 at all call sites
    const int wgid = bx + gx * (by + gy * bz);
    const int swz = (wgid & 7) * (nwg >> 3) + (wgid >> 3);
    bx = swz % gx; const int t = swz / gx; by = t % gy; bz = t / gy;
  }
  const int n0 = bx * 128, m0 = by * 128;
  if (CSKIP && n0 > m0 + 127) return;
  A  += (size_t)bsA * bz;
  Bt += (size_t)bsB * bz;

  __shared__ unsigned short As[3 * 128 * 32];  // unpadded: required by global_load_lds
  __shared__ unsigned short Bs[3 * 128 * 32];

  const int tid  = threadIdx.x;
  const int lane = tid & 63, wid = tid >> 6;
  const int wm = (wid >> 1) * 64, wn = (wid & 1) * 64;
  const int fr = lane & 15, kc = (lane >> 4) * 8;

  f32x4 acc[4][4] = {};

  int ktEnd = K >> 5;
  if (CKLIM) { int lim = (m0 + 128) >> 5; if (lim < ktEnd) ktEnd = lim; }

  // strength-reduced staging pointers: chunk ch = wid*64 + i*256 + lane (16B each)
  const int ch0 = wid * 64 + lane;
  const int rA0 = ch0 >> 2, rA1 = rA0 + 64, c8s = (ch0 & 3) * 8;
  const unsigned short* pA0 = A  + (size_t)(m0 + rA0) * lda + c8s;
  const unsigned short* pA1 = A  + (size_t)(m0 + rA1) * lda + c8s;
  const unsigned short* pB0 = Bt + (size_t)(n0 + rA0) * ldb + c8s;
  const unsigned short* pB1 = Bt + (size_t)(n0 + rA1) * ldb + c8s;
  const int lb0 = (wid * 64) * 16, lb1 = (wid * 64 + 256) * 16;  // wave-uniform LDS bases

#define STAGE_AT(OE)                                   \
  async16(pA0, (char*)(As + (OE)) + lb0);              \
  async16(pA1, (char*)(As + (OE)) + lb1);              \
  async16(pB0, (char*)(Bs + (OE)) + lb0);              \
  async16(pB1, (char*)(Bs + (OE)) + lb1);              \
  pA0 += 32; pA1 += 32; pB0 += 32; pB1 += 32;

#define COMPUTE_AT(OE)                                                                      \
  {                                                                                         \
    short8 af[4], bfr[4];                                                                   \
    _Pragma("unroll")                                                                       \
    for (int i = 0; i < 4; ++i) af[i]  = *reinterpret_cast<const short8*>(&As[(OE) + (wm + i * 16 + fr) * 32 + kc]); \
    _Pragma("unroll")                                                                       \
    for (int i = 0; i < 4; ++i) bfr[i] = *reinterpret_cast<const short8*>(&Bs[(OE) + (wn + i * 16 + fr) * 32 + kc]); \
    _Pragma("unroll")                                                                       \
    for (int mi = 0; mi < 4; ++mi)                                                          \
      _Pragma("unroll")                                                                     \
      for (int ni = 0; ni < 4; ++ni)                                                        \
        acc[mi][ni] = __builtin_amdgcn_mfma_f32_16x16x32_bf16(af[mi], bfr[ni], acc[mi][ni], 0, 0, 0); \
  }

  // prologue: stage tiles 0 and 1 into buffers 0 and 1
  STAGE_AT(0);
  if (ktEnd > 1) { STAGE_AT(4096); }
  if (ktEnd > 1) asm volatile("s_waitcnt vmcnt(4)" ::: "memory");   // tile 0 landed
  else           asm volatile("s_waitcnt vmcnt(0)" ::: "memory");
  __builtin_amdgcn_s_barrier();

  int o0 = 0, o1 = 4096, o2 = 8192;     // compute / next-ready / stage-target
  for (int kt = 0; kt + 2 < ktEnd; ++kt) {
    STAGE_AT(o2);                       // issue tile kt+2
    COMPUTE_AT(o0);                     // compute tile kt
    asm volatile("s_waitcnt vmcnt(4) lgkmcnt(0)" ::: "memory");     // tile kt+1 ready
    __builtin_amdgcn_s_barrier();
    const int tt = o0; o0 = o1; o1 = o2; o2 = tt;
  }
  if (ktEnd > 1) {                      // tile ktEnd-2 (no more prefetch)
    COMPUTE_AT(o0);
    asm volatile("s_waitcnt vmcnt(0) lgkmcnt(0)" ::: "memory");     // last tile ready
    __builtin_amdgcn_s_barrier();
    const int tt = o0; o0 = o1; o1 = o2; o2 = tt;
  }
  COMPUTE_AT(o0);                       // tile ktEnd-1

#undef STAGE_AT
#undef COMPUTE_AT

  // C/D layout: col = lane&15, row = (lane>>4)*4 + j   [m89/m91-verified]
  const int cc = lane & 15, r4 = (lane >> 4) * 4;
  const size_t cb = (size_t)bsC * bz;

  float bvv[4];
  #pragma unroll
  for (int ni = 0; ni < 4; ++ni) bvv[ni] = BIAS ? bias[n0 + wn + ni * 16 + cc] : 0.f;

  if (OF32) {
    float* outF = (float*)outv + cb + (size_t)(m0 + wm + r4) * ldc + n0 + wn + cc;
    #pragma unroll
    for (int mi = 0; mi < 4; ++mi) {
      #pragma unroll
      for (int j = 0; j < 4; ++j) {
        float* rp = outF + (size_t)(mi * 16 + j) * ldc;
        #pragma unroll
        for (int ni = 0; ni < 4; ++ni) {
          float v;
          if (BIAS) v = SCALED ? fmaf(acc[mi][ni][j], scale, bvv[ni]) : acc[mi][ni][j] + bvv[ni];
          else      v = SCALED ? acc[mi][ni][j] * scale               : acc[mi][ni][j];
          if (RELU) v = fmaxf(v, 0.f);
          rp[ni * 16] = v;
        }
      }
    }
  } else {
    unsigned short* outB = (unsigned short*)outv + cb + (size_t)(m0 + wm + r4) * ldc + n0 + wn + cc;
    #pragma unroll
    for (int mi = 0; mi < 4; ++mi) {
      #pragma unroll
      for (int j = 0; j < 4; ++j) {
        unsigned short* rp = outB + (size_t)(mi * 16 + j) * ldc;
        #pragma unroll
        for (int ni = 0; ni < 4; ++ni) {
          float v;
          if (BIAS) v = SCALED ? fmaf(acc[mi][ni][j], scale, bvv[ni]) : acc[mi][ni][j] + bvv[ni];
          else      v = SCALED ? acc[mi][ni][j] * scale               : acc[mi][ni][j];
          if (RELU) v = fmaxf(v, 0.f);
          rp[ni * 16] = f2b(v);
        }
      }
    }
  }
}

// ================= batched 5-way weight transpose fp32 -> bf16T =================
__global__ __launch_bounds__(256) void wtrans5(
    const float* __restrict__ w0, const float* __restrict__ w1,
    const float* __restrict__ w2, const float* __restrict__ w3,
    const float* __restrict__ w4, unsigned short* __restrict__ base)
{
  __shared__ unsigned short t[64][80];
  const int z = blockIdx.z;
  const float* src = (z == 0) ? w0 : (z == 1) ? w1 : (z == 2) ? w2 : (z == 3) ? w3 : w4;
  unsigned short* dst = base + (size_t)z * 1024 * 1024;
  const int c0 = blockIdx.x * 64, r0 = blockIdx.y * 64;
  const int tid = threadIdx.x;
  const int lr = tid >> 2, lc = (tid & 3) * 16;

  const float* s = src + (size_t)(r0 + lr) * 1024 + c0 + lc;
  #pragma unroll
  for (int j = 0; j < 16; j += 4) {
    const float4 v = *reinterpret_cast<const float4*>(s + j);
    t[lr][lc + j + 0] = f2b(v.x); t[lr][lc + j + 1] = f2b(v.y);
    t[lr][lc + j + 2] = f2b(v.z); t[lr][lc + j + 3] = f2b(v.w);
  }
  __syncthreads();

  unsigned short* dp = dst + (size_t)(c0 + lr) * 1024 + r0 + lc;
  U8 o0, o1;
  #pragma unroll
  for (int j = 0; j < 8; ++j) { o0.s[j] = t[lc + j][lr]; o1.s[j] = t[lc + 8 + j][lr]; }
  *reinterpret_cast<uint4*>(dp)     = o0.v;
  *reinterpret_cast<uint4*>(dp + 8) = o1.v;
}

// ================= bf16 transpose (for V^T) =================
__global__ __launch_bounds__(256) void trans_b(
    const unsigned short* __restrict__ src, unsigned short* __restrict__ dst,
    int sld, int dld, long long sbs, long long dbs, int scol)
{
  __shared__ unsigned short t[64][80];
  const int c0 = blockIdx.x * 64, r0 = blockIdx.y * 64;
  const int tid = threadIdx.x;
  const int lr = tid >> 2, lc = (tid & 3) * 16;

  const unsigned short* s = src + (size_t)sbs * blockIdx.z + (size_t)(r0 + lr) * sld + scol + c0 + lc;
  *reinterpret_cast<uint4*>(&t[lr][lc])     = *reinterpret_cast<const uint4*>(s);
  *reinterpret_cast<uint4*>(&t[lr][lc + 8]) = *reinterpret_cast<const uint4*>(s + 8);
  __syncthreads();

  unsigned short* dp = dst + (size_t)dbs * blockIdx.z + (size_t)(c0 + lr) * dld + r0 + lc;
  U8 o0, o1;
  #pragma unroll
  for (int j = 0; j < 8; ++j) { o0.s[j] = t[lc + j][lr]; o1.s[j] = t[lc + 8 + j][lr]; }
  *reinterpret_cast<uint4*>(dp)     = o0.v;
  *reinterpret_cast<uint4*>(dp + 8) = o1.v;
}

// ================= fp32 -> bf16 bulk convert =================
__global__ __launch_bounds__(256) void cvt_kernel(const float* __restrict__ in,
                                                  unsigned short* __restrict__ out, int n4)
{
  int i = blockIdx.x * 256 + threadIdx.x;
  if (i < n4) {
    const float4 v = reinterpret_cast<const float4*>(in)[i];
    ushort4 o; o.x = f2b(v.x); o.y = f2b(v.y); o.z = f2b(v.z); o.w = f2b(v.w);
    reinterpret_cast<ushort4*>(out)[i] = o;
  }
}

// ================= bias concat: bcat[3072] = {bq, bk, bv} =================
__global__ __launch_bounds__(1024) void bias3_k(
    const float* __restrict__ b0, const float* __restrict__ b1,
    const float* __restrict__ b2, float* __restrict__ out)
{
  const int z = blockIdx.x, tid = threadIdx.x;
  const float* s = (z == 0) ? b0 : (z == 1) ? b1 : b2;
  out[z * 1024 + tid] = s[tid];
}

// ================= causal row softmax (fp32 in place, optional bf16 dual write) ======
template<int DUAL>
__global__ __launch_bounds__(256) void softmax_f32(float* __restrict__ w,
                                                   unsigned short* __restrict__ pb)
{
  const int S = 2048;
  const int gr = blockIdx.x;          // b*S + q
  const int q = gr & (S - 1);
  float* row = w + (size_t)gr * S;
  const int valid = q + 1;
  const int tid = threadIdx.x, lane = tid & 63, wv = tid >> 6;
  __shared__ float red[8];

  const int e0 = tid * 4, e1 = (tid + 256) * 4;
  float4 v0 = make_float4(0.f, 0.f, 0.f, 0.f), v1 = v0;
  if (e0 < valid) v0 = reinterpret_cast<const float4*>(row)[tid];        // causal read-skip
  if (e1 < valid) v1 = reinterpret_cast<const float4*>(row)[tid + 256];
  float a[8] = { v0.x, v0.y, v0.z, v0.w, v1.x, v1.y, v1.z, v1.w };
  const int idx[8] = { e0, e0+1, e0+2, e0+3, e1, e1+1, e1+2, e1+3 };

  float m = -3.0e38f;
  #pragma unroll
  for (int j = 0; j < 8; ++j) if (idx[j] < valid) m = fmaxf(m, a[j]);
  #pragma unroll
  for (int o = 32; o; o >>= 1) m = fmaxf(m, __shfl_down(m, o, 64));
  if (lane == 0) red[wv] = m;
  __syncthreads();
  m = fmaxf(fmaxf(red[0], red[1]), fmaxf(red[2], red[3]));

  float s = 0.f;
  #pragma unroll
  for (int j = 0; j < 8; ++j) {
    a[j] = (idx[j] < valid) ? __expf(a[j] - m) : 0.f;
    s += a[j];
  }
  #pragma unroll
  for (int o = 32; o; o >>= 1) s += __shfl_down(s, o, 64);
  if (lane == 0) red[4 + wv] = s;
  __syncthreads();
  s = red[4] + red[5] + red[6] + red[7];
  const float inv = 1.f / s;

  #pragma unroll
  for (int j = 0; j < 8; ++j) a[j] *= inv;
  reinterpret_cast<float4*>(row)[tid]       = make_float4(a[0], a[1], a[2], a[3]);
  reinterpret_cast<float4*>(row)[tid + 256] = make_float4(a[4], a[5], a[6], a[7]);
  if (DUAL) {
    // PV reads K-blocks of 128 up to ceil(valid/128); beyond that Pb is never read.
    const int plim = ((q >> 7) + 1) << 7;
    unsigned short* pr = pb + (size_t)gr * S;
    if (e0 < plim) {
      ushort4 p0;
      p0.x = f2b(a[0]); p0.y = f2b(a[1]); p0.z = f2b(a[2]); p0.w = f2b(a[3]);
      reinterpret_cast<ushort4*>(pr)[tid] = p0;
    }
    if (e1 < plim) {
      ushort4 p1;
      p1.x = f2b(a[4]); p1.y = f2b(a[5]); p1.z = f2b(a[6]); p1.w = f2b(a[7]);
      reinterpret_cast<ushort4*>(pr)[tid + 256] = p1;
    }
  }
}

// ================= residual + LayerNorm =================
DEV float blockSum(float v, float* red) {
  #pragma unroll
  for (int o = 32; o; o >>= 1) v += __shfl_down(v, o, 64);
  const int lane = threadIdx.x & 63, wv = threadIdx.x >> 6;
  if (lane == 0) red[wv] = v;
  __syncthreads();
  float r = red[0] + red[1] + red[2] + red[3];
  __syncthreads();
  return r;
}

template<int AF32, int OF32>
__global__ __launch_bounds__(256) void ln_k(
    const void* __restrict__ xav, const unsigned short* __restrict__ xb,
    const float* __restrict__ g, const float* __restrict__ be,
    void* __restrict__ outv)
{
  const int D = 1024;
  const int r = blockIdx.x, tid = threadIdx.x;
  float a0, a1, a2, a3;
  if (AF32) {
    const float4 va = reinterpret_cast<const float4*>((const float*)xav + (size_t)r * D)[tid];
    a0 = va.x; a1 = va.y; a2 = va.z; a3 = va.w;
  } else {
    const ushort4 va = reinterpret_cast<const ushort4*>((const unsigned short*)xav + (size_t)r * D)[tid];
    a0 = b2f(va.x); a1 = b2f(va.y); a2 = b2f(va.z); a3 = b2f(va.w);
  }
  const ushort4 vb = reinterpret_cast<const ushort4*>(xb + (size_t)r * D)[tid];
  const float x0 = a0 + b2f(vb.x), x1 = a1 + b2f(vb.y);
  const float x2 = a2 + b2f(vb.z), x3 = a3 + b2f(vb.w);
  __shared__ float red[4];
  const float S1 = blockSum(x0 + x1 + x2 + x3, red);
  const float S2 = blockSum(x0*x0 + x1*x1 + x2*x2 + x3*x3, red);
  const float mu  = S1 * (1.f / 1024.f);
  const float var = S2 * (1.f / 1024.f) - mu * mu;
  const float rs  = rsqrtf(var + 1e-5f);
  const float4 gv = reinterpret_cast<const float4*>(g)[tid];
  const float4 bv = reinterpret_cast<const float4*>(be)[tid];
  const float o0 = (x0 - mu) * rs * gv.x + bv.x;
  const float o1 = (x1 - mu) * rs * gv.y + bv.y;
  const float o2 = (x2 - mu) * rs * gv.z + bv.z;
  const float o3 = (x3 - mu) * rs * gv.w + bv.w;
  if (OF32) {
    reinterpret_cast<float4*>((float*)outv + (size_t)r * D)[tid] = make_float4(o0, o1, o2, o3);
  } else {
    ushort4 ob; ob.x = f2b(o0); ob.y = f2b(o1); ob.z = f2b(o2); ob.w = f2b(o3);
    reinterpret_cast<ushort4*>((unsigned short*)outv + (size_t)r * D)[tid] = ob;
  }
}

// ================= fallback reg-staged GEMM (round-3, for small ws) =================
template<int TB, int AF32, int BF32, int BIAS, int RELU, int OF32, int CSKIP, int CKLIM>
__global__ __launch_bounds__(256) void gemm_rs(
    const void* __restrict__ Av, const void* __restrict__ Bv,
    const float* __restrict__ bias, void* __restrict__ outv,
    int K, int lda, int ldb, int ldc,
    long long bsA, long long bsB, long long bsC, float scale)
{
  const int n0 = blockIdx.x * 128, m0 = blockIdx.y * 128;
  if (CSKIP && n0 > m0 + 127) return;
  const size_t zA = (size_t)bsA * blockIdx.z;
  const size_t zB = (size_t)bsB * blockIdx.z;
  const float*          Afp = (const float*)Av;
  const unsigned short* Abf = (const unsigned short*)Av;
  const float*          Bfp = (const float*)Bv;
  const unsigned short* Bbf = (const unsigned short*)Bv;

  __shared__ unsigned short As[128][40];
  __shared__ unsigned short Bs[128][40];

  const int tid  = threadIdx.x;
  const int lane = tid & 63, wid = tid >> 6;
  const int wm = (wid >> 1) * 64, wn = (wid & 1) * 64;
  const int fr = lane & 15, kc = (lane >> 4) * 8;

  f32x4 acc[4][4] = {};
  int ktEnd = K >> 5;
  if (CKLIM) { int lim = (m0 + 128) >> 5; if (lim < ktEnd) ktEnd = lim; }

  for (int kt = 0; kt < ktEnd; ++kt) {
    __syncthreads();
    #pragma unroll
    for (int i = 0; i < 2; ++i) {
      const int ff = tid + i * 256;
      const int r = ff >> 2, c8 = (ff & 3) * 8;
      const size_t off = zA + (size_t)(m0 + r) * lda + kt * 32 + c8;
      U8 u;
      if (AF32) {
        const float4 v0 = *reinterpret_cast<const float4*>(Afp + off);
        const float4 v1 = *reinterpret_cast<const float4*>(Afp + off + 4);
        u.s[0]=f2b(v0.x); u.s[1]=f2b(v0.y); u.s[2]=f2b(v0.z); u.s[3]=f2b(v0.w);
        u.s[4]=f2b(v1.x); u.s[5]=f2b(v1.y); u.s[6]=f2b(v1.z); u.s[7]=f2b(v1.w);
      } else u.v = *reinterpret_cast<const uint4*>(Abf + off);
      *reinterpret_cast<uint4*>(&As[r][c8]) = u.v;
    }
    if (TB) {
      #pragma unroll
      for (int i = 0; i < 2; ++i) {
        const int ff = tid + i * 256;
        const int r = ff >> 2, c8 = (ff & 3) * 8;
        const size_t off = zB + (size_t)(n0 + r) * ldb + kt * 32 + c8;
        U8 u;
        if (BF32) {
          const float4 v0 = *reinterpret_cast<const float4*>(Bfp + off);
          const float4 v1 = *reinterpret_cast<const float4*>(Bfp + off + 4);
          u.s[0]=f2b(v0.x); u.s[1]=f2b(v0.y); u.s[2]=f2b(v0.z); u.s[3]=f2b(v0.w);
          u.s[4]=f2b(v1.x); u.s[5]=f2b(v1.y); u.s[6]=f2b(v1.z); u.s[7]=f2b(v1.w);
        } else u.v = *reinterpret_cast<const uint4*>(Bbf + off);
        *reinterpret_cast<uint4*>(&Bs[r][c8]) = u.v;
      }
    } else {
      #pragma unroll
      for (int i = 0; i < 2; ++i) {
        const int ff = tid + i * 256;
        const int k = ff >> 4, c8 = (ff & 15) * 8;
        const size_t off = zB + (size_t)(kt * 32 + k) * ldb + n0 + c8;
        U8 u;
        if (BF32) {
          const float4 v0 = *reinterpret_cast<const float4*>(Bfp + off);
          const float4 v1 = *reinterpret_cast<const float4*>(Bfp + off + 4);
          u.s[0]=f2b(v0.x); u.s[1]=f2b(v0.y); u.s[2]=f2b(v0.z); u.s[3]=f2b(v0.w);
          u.s[4]=f2b(v1.x); u.s[5]=f2b(v1.y); u.s[6]=f2b(v1.z); u.s[7]=f2b(v1.w);
        } else u.v = *reinterpret_cast<const uint4*>(Bbf + off);
        #pragma unroll
        for (int j = 0; j < 8; ++j) Bs[c8 + j][k] = u.s[j];
      }
    }
    __syncthreads();

    short8 af[4], bfr[4];
    #pragma unroll
    for (int i = 0; i < 4; ++i) af[i]  = *reinterpret_cast<const short8*>(&As[wm + i * 16 + fr][kc]);
    #pragma unroll
    for (int i = 0; i < 4; ++i) bfr[i] = *reinterpret_cast<const short8*>(&Bs[wn + i * 16 + fr][kc]);
    #pragma unroll
    for (int mi = 0; mi < 4; ++mi)
      #pragma unroll
      for (int ni = 0; ni < 4; ++ni)
        acc[mi][ni] = __builtin_amdgcn_mfma_f32_16x16x32_bf16(af[mi], bfr[ni], acc[mi][ni], 0, 0, 0);
  }

  const int cc = lane & 15, r4 = (lane >> 4) * 4;
  const size_t cb = (size_t)bsC * blockIdx.z;
  float*          outF = (float*)outv;
  unsigned short* outB = (unsigned short*)outv;
  #pragma unroll
  for (int mi = 0; mi < 4; ++mi) {
    #pragma unroll
    for (int ni = 0; ni < 4; ++ni) {
      const int col = n0 + wn + ni * 16 + cc;
      const float bv = BIAS ? bias[col] : 0.f;
      #pragma unroll
      for (int j = 0; j < 4; ++j) {
        const int row = m0 + wm + mi * 16 + r4 + j;
        float v = acc[mi][ni][j] * scale + bv;
        if (RELU) v = fmaxf(v, 0.f);
        if (OF32) outF[cb + (size_t)row * ldc + col] = v;
        else      outB[cb + (size_t)row * ldc + col] = f2b(v);
      }
    }
  }
}

// ================= launch =================
extern "C" void kernel_launch(void* const* d_in, const int* in_sizes, int n_in,
                              void* d_out, int out_size, void* d_ws, size_t ws_size,
                              hipStream_t stream)
{
  (void)in_sizes; (void)n_in; (void)out_size;
  const int B = 4, S = 2048, D = 1024;
  const int M = B * S;
  const long long SD = (long long)S * D, SS = (long long)S * S;
  const size_t MB = 1024 * 1024;

  const float* x   = (const float*)d_in[0];
  const float* Wq  = (const float*)d_in[1];  const float* bq  = (const float*)d_in[2];
  const float* Wk  = (const float*)d_in[3];  const float* bk  = (const float*)d_in[4];
  const float* Wv  = (const float*)d_in[5];  const float* bv  = (const float*)d_in[6];
  const float* W1  = (const float*)d_in[7];  const float* b1  = (const float*)d_in[8];
  const float* W2  = (const float*)d_in[9];  const float* b2  = (const float*)d_in[10];
  const float* g1  = (const float*)d_in[11]; const float* be1 = (const float*)d_in[12];
  const float* g2  = (const float*)d_in[13]; const float* be2 = (const float*)d_in[14];

  float* out0f = (float*)d_out;                 // [B,S,D] fp32 (written by final LN)
  float* woutf = out0f + (size_t)M * D;         // [B,S,S] fp32 weights

  if (ws_size >= 112 * MB + 16384) {
    // ---------- tier A: all-bf16 GLL pipeline ----------
    char* ws = (char*)d_ws;
    unsigned short* xb   = (unsigned short*)(ws);            // [0,16M) -> h after QKV
    unsigned short* QKVb = (unsigned short*)(ws + 16 * MB);  // [16M,64M) [8192,3072]
    unsigned short* VT   = (unsigned short*)(ws + 64 * MB);  // [64M,80M) [B,1024,2048]
    unsigned short* Pb   = (unsigned short*)(ws + 80 * MB);  // [80M,112M) [B,S,S]
    float*          bcat = (float*)(ws + 112 * MB);          // [3072]
    unsigned short* h    = xb;                               // reuse (xb dead after QKV)
    unsigned short* attn = QKVb;                             // reuse Q region
    unsigned short* f2   = QKVb + 8 * MB;                    // reuse K region (u16: +16MB)

    unsigned short* outu = (unsigned short*)d_out;           // out0 region (dead till LN2)
    unsigned short* WqkvT = outu;                            // [3072][1024] bf16, 6 MB
    unsigned short* W1T   = outu + 3072 * 1024;              // 2 MB
    unsigned short* W2T   = outu + 4096 * 1024;              // 2 MB
    unsigned short* f1    = outu + 8 * MB;                   // [16MB,32MB) of out0

    // 1. convert / transpose operands (batched)
    cvt_kernel<<<M * D / 4 / 256, 256, 0, stream>>>(x, xb, M * D / 4);
    bias3_k<<<3, 1024, 0, stream>>>(bq, bk, bv, bcat);
    wtrans5<<<dim3(16, 16, 5), 256, 0, stream>>>(Wq, Wk, Wv, W1, W2, WqkvT);

    // 2. merged QKV projection: [8192,3072]  (scale==1 -> SCALED=0)
    gemm_gll<1,0,0,0,0,0><<<dim3(24, 64, 1), 256, 0, stream>>>(xb, WqkvT, bcat, QKVb,
        D, D, D, 3072, 0, 0, 0, 1.f);

    // 3. V^T per batch: [1024,2048]
    trans_b<<<dim3(16, 32, 4), 256, 0, stream>>>(QKVb, VT, 3072, 2048,
        2048LL * 3072, 1024LL * 2048, 2048);

    // 4. scores = Q K^T / 32 -> fp32 weights (causal blocks skipped)
    gemm_gll<0,0,1,1,1,0><<<dim3(16, 16, 4), 256, 0, stream>>>(QKVb, QKVb + 1024, nullptr, woutf,
        D, 3072, 3072, S, 2048LL * 3072, 2048LL * 3072, SS, 1.f / 32.f);

    // 5. softmax in place + bf16 dual write (skip P-writes beyond diag block)
    softmax_f32<1><<<B * S, 256, 0, stream>>>(woutf, Pb);

    // 6. attn = P V  (A=Pb bf16, B=VT, K clipped) -> attn bf16
    gemm_gll<0,0,0,0,0,1><<<dim3(8, 16, 4), 256, 0, stream>>>(Pb, VT, nullptr, attn,
        S, S, S, D, SS, (long long)D * S, SD, 1.f);

    // 7. h = LN(x + attn)
    ln_k<1,0><<<M, 256, 0, stream>>>(x, attn, g1, be1, h);

    // 8. f1 = relu(h W1T^T + b1)
    gemm_gll<1,1,0,0,0,0><<<dim3(8, 64, 1), 256, 0, stream>>>(h, W1T, b1, f1,
        D, D, D, D, 0, 0, 0, 1.f);

    // 9. f2 = f1 W2T^T + b2
    gemm_gll<1,0,0,0,0,0><<<dim3(8, 64, 1), 256, 0, stream>>>(f1, W2T, b2, f2,
        D, D, D, D, 0, 0, 0, 1.f);

    // 10. out = LN(h + f2) -> fp32
    ln_k<0,1><<<M, 256, 0, stream>>>(h, f2, g2, be2, out0f);
  } else {
    // ---------- tier C: round-3 fallback (32 MB ws) ----------
    unsigned short* slot0 = (unsigned short*)d_ws;
    unsigned short* slot1 = (unsigned short*)((char*)d_ws + (size_t)M * D * 2);
    unsigned short* Vb  = (unsigned short*)d_out;
    unsigned short* f1b = (unsigned short*)d_out;

    dim3 gProj(D / 128, M / 128, 1);
    dim3 gSc(S / 128, S / 128, B);
    dim3 gPV(D / 128, S / 128, B);

    gemm_rs<0,1,1,1,0,0,0,0><<<gProj, 256, 0, stream>>>(x, Wq, bq, slot0, D, D, D, D, 0, 0, 0, 1.f);
    gemm_rs<0,1,1,1,0,0,0,0><<<gProj, 256, 0, stream>>>(x, Wk, bk, slot1, D, D, D, D, 0, 0, 0, 1.f);
    gemm_rs<0,1,1,1,0,0,0,0><<<gProj, 256, 0, stream>>>(x, Wv, bv, Vb,    D, D, D, D, 0, 0, 0, 1.f);
    gemm_rs<1,0,0,0,0,1,1,0><<<gSc, 256, 0, stream>>>(slot0, slot1, nullptr, woutf,
        D, D, D, S, SD, SD, SS, 1.f / 32.f);
    softmax_f32<0><<<B * S, 256, 0, stream>>>(woutf, nullptr);
    gemm_rs<0,1,0,0,0,0,0,1><<<gPV, 256, 0, stream>>>(woutf, Vb, nullptr, slot0,
        S, S, D, D, SS, SD, SD, 1.f);
    ln_k<1,0><<<M, 256, 0, stream>>>(x, slot0, g1, be1, slot1);
    gemm_rs<0,0,1,1,1,0,0,0><<<gProj, 256, 0, stream>>>(slot1, W1, b1, f1b, D, D, D, D, 0, 0, 0, 1.f);
    gemm_rs<0,0,1,1,0,0,0,0><<<gProj, 256, 0, stream>>>(f1b, W2, b2, slot0, D, D, D, D, 0, 0, 0, 1.f);
    ln_k<0,1><<<M, 256, 0, stream>>>(slot1, slot0, g2, be2, out0f);
  }
}

// Round 14
// 294.109 us; speedup vs baseline: 1.0589x; 1.0589x over previous
//
#include <hip/hip_runtime.h>
#include <hip/hip_bf16.h>
#include <cstdint>

typedef __attribute__((ext_vector_type(8))) short short8;
typedef __attribute__((ext_vector_type(4))) float f32x4;

#define DEV static __device__ __forceinline__

DEV float b2f(unsigned short u) {
  union { unsigned int i; float f; } c; c.i = ((unsigned int)u) << 16; return c.f;
}
DEV unsigned short f2b(float f) {
  __hip_bfloat16 h = __float2bfloat16(f);          // HW cvt, RNE
  return *reinterpret_cast<unsigned short*>(&h);
}

DEV void async16(const void* g, void* l) {
  __builtin_amdgcn_global_load_lds((__attribute__((address_space(1))) void*)g,
                                   (__attribute__((address_space(3))) void*)l, 16, 0, 0);
}

union U8 { uint4 v; unsigned short s[8]; };

// ================= fast path: bf16 GEMM, global_load_lds + XOR-offset 2-phase =========
// C[M,N] = scale * A @ Bt^T + bias.  A [M,K] bf16 row-major, Bt [N,K] bf16 row-major.
// Round-12 structure == best measured (294 us). Counted-vmcnt 3-buffer variants
// (r11, r13) both regressed: VALUBusy 18.6 -> 46% from asm-waitcnt scheduling damage.
template<int BIAS, int RELU, int OF32, int SCALED, int CSKIP, int CKLIM>
__global__ __launch_bounds__(256) void gemm_gll(
    const unsigned short* __restrict__ A, const unsigned short* __restrict__ Bt,
    const float* __restrict__ bias, void* __restrict__ outv,
    int K, int lda, int ldb, int ldc,
    long long bsA, long long bsB, long long bsC, float scale)
{
  // --- XCD swizzle: each XCD gets a contiguous chunk of the linearized grid ---
  int bx = blockIdx.x, by = blockIdx.y, bz = blockIdx.z;
  {
    const int gx = gridDim.x, gy = gridDim.y;
    const int nwg = gx * gy * gridDim.z;          // divisible by 8 at all call sites
    const int wgid = bx + gx * (by + gy * bz);
    const int swz = (wgid & 7) * (nwg >> 3) + (wgid >> 3);
    bx = swz % gx; const int t = swz / gx; by = t % gy; bz = t / gy;
  }
  const int n0 = bx * 128, m0 = by * 128;
  if (CSKIP && n0 > m0 + 127) return;
  A  += (size_t)bsA * bz;
  Bt += (size_t)bsB * bz;

  __shared__ unsigned short As[2 * 128 * 32];  // unpadded: required by global_load_lds
  __shared__ unsigned short Bs[2 * 128 * 32];

  const int tid  = threadIdx.x;
  const int lane = tid & 63, wid = tid >> 6;
  const int wm = (wid >> 1) * 64, wn = (wid & 1) * 64;
  const int fr = lane & 15, kc = (lane >> 4) * 8;

  f32x4 acc[4][4] = {};

  int ktEnd = K >> 5;
  if (CKLIM) { int lim = (m0 + 128) >> 5; if (lim < ktEnd) ktEnd = lim; }

  // strength-reduced staging pointers: chunk ch = wid*64 + i*256 + lane (16B each)
  const int ch0 = wid * 64 + lane;
  const int rA0 = ch0 >> 2, rA1 = rA0 + 64, c8s = (ch0 & 3) * 8;
  const unsigned short* pA0 = A  + (size_t)(m0 + rA0) * lda + c8s;
  const unsigned short* pA1 = A  + (size_t)(m0 + rA1) * lda + c8s;
  const unsigned short* pB0 = Bt + (size_t)(n0 + rA0) * ldb + c8s;
  const unsigned short* pB1 = Bt + (size_t)(n0 + rA1) * ldb + c8s;
  const int lb0 = (wid * 64) * 16, lb1 = (wid * 64 + 256) * 16;  // wave-uniform LDS bases

  // prologue: stage tile 0 into offset 0
  async16(pA0, (char*)As + lb0);
  async16(pA1, (char*)As + lb1);
  async16(pB0, (char*)Bs + lb0);
  async16(pB1, (char*)Bs + lb1);
  pA0 += 32; pA1 += 32; pB0 += 32; pB1 += 32;
  __syncthreads();                       // implicit vmcnt(0): tile 0 landed

  int oe = 0;
  for (int kt = 0; kt < ktEnd; ++kt) {
    const int onext = oe ^ 4096;
    if (kt + 1 < ktEnd) {                // issue next tile's loads EARLY
      async16(pA0, (char*)(As + onext) + lb0);
      async16(pA1, (char*)(As + onext) + lb1);
      async16(pB0, (char*)(Bs + onext) + lb0);
      async16(pB1, (char*)(Bs + onext) + lb1);
      pA0 += 32; pA1 += 32; pB0 += 32; pB1 += 32;
    }
    short8 af[4], bfr[4];
    #pragma unroll
    for (int i = 0; i < 4; ++i) af[i]  = *reinterpret_cast<const short8*>(&As[oe + (wm + i * 16 + fr) * 32 + kc]);
    #pragma unroll
    for (int i = 0; i < 4; ++i) bfr[i] = *reinterpret_cast<const short8*>(&Bs[oe + (wn + i * 16 + fr) * 32 + kc]);
    #pragma unroll
    for (int mi = 0; mi < 4; ++mi)
      #pragma unroll
      for (int ni = 0; ni < 4; ++ni)
        acc[mi][ni] = __builtin_amdgcn_mfma_f32_16x16x32_bf16(af[mi], bfr[ni], acc[mi][ni], 0, 0, 0);
    __syncthreads();                     // drains prefetch (vmcnt 0) + syncs LDS reads
    oe = onext;
  }

  // C/D layout: col = lane&15, row = (lane>>4)*4 + j   [m89/m91-verified]
  const int cc = lane & 15, r4 = (lane >> 4) * 4;
  const size_t cb = (size_t)bsC * bz;

  float bvv[4];
  #pragma unroll
  for (int ni = 0; ni < 4; ++ni) bvv[ni] = BIAS ? bias[n0 + wn + ni * 16 + cc] : 0.f;

  if (OF32) {
    float* outF = (float*)outv + cb + (size_t)(m0 + wm + r4) * ldc + n0 + wn + cc;
    #pragma unroll
    for (int mi = 0; mi < 4; ++mi) {
      #pragma unroll
      for (int j = 0; j < 4; ++j) {
        float* rp = outF + (size_t)(mi * 16 + j) * ldc;
        #pragma unroll
        for (int ni = 0; ni < 4; ++ni) {
          float v;
          if (BIAS) v = SCALED ? fmaf(acc[mi][ni][j], scale, bvv[ni]) : acc[mi][ni][j] + bvv[ni];
          else      v = SCALED ? acc[mi][ni][j] * scale               : acc[mi][ni][j];
          if (RELU) v = fmaxf(v, 0.f);
          rp[ni * 16] = v;
        }
      }
    }
  } else {
    unsigned short* outB = (unsigned short*)outv + cb + (size_t)(m0 + wm + r4) * ldc + n0 + wn + cc;
    #pragma unroll
    for (int mi = 0; mi < 4; ++mi) {
      #pragma unroll
      for (int j = 0; j < 4; ++j) {
        unsigned short* rp = outB + (size_t)(mi * 16 + j) * ldc;
        #pragma unroll
        for (int ni = 0; ni < 4; ++ni) {
          float v;
          if (BIAS) v = SCALED ? fmaf(acc[mi][ni][j], scale, bvv[ni]) : acc[mi][ni][j] + bvv[ni];
          else      v = SCALED ? acc[mi][ni][j] * scale               : acc[mi][ni][j];
          if (RELU) v = fmaxf(v, 0.f);
          rp[ni * 16] = f2b(v);
        }
      }
    }
  }
}

// ================= batched 5-way weight transpose fp32 -> bf16T =================
__global__ __launch_bounds__(256) void wtrans5(
    const float* __restrict__ w0, const float* __restrict__ w1,
    const float* __restrict__ w2, const float* __restrict__ w3,
    const float* __restrict__ w4, unsigned short* __restrict__ base)
{
  __shared__ unsigned short t[64][80];
  const int z = blockIdx.z;
  const float* src = (z == 0) ? w0 : (z == 1) ? w1 : (z == 2) ? w2 : (z == 3) ? w3 : w4;
  unsigned short* dst = base + (size_t)z * 1024 * 1024;
  const int c0 = blockIdx.x * 64, r0 = blockIdx.y * 64;
  const int tid = threadIdx.x;
  const int lr = tid >> 2, lc = (tid & 3) * 16;

  const float* s = src + (size_t)(r0 + lr) * 1024 + c0 + lc;
  #pragma unroll
  for (int j = 0; j < 16; j += 4) {
    const float4 v = *reinterpret_cast<const float4*>(s + j);
    t[lr][lc + j + 0] = f2b(v.x); t[lr][lc + j + 1] = f2b(v.y);
    t[lr][lc + j + 2] = f2b(v.z); t[lr][lc + j + 3] = f2b(v.w);
  }
  __syncthreads();

  unsigned short* dp = dst + (size_t)(c0 + lr) * 1024 + r0 + lc;
  U8 o0, o1;
  #pragma unroll
  for (int j = 0; j < 8; ++j) { o0.s[j] = t[lc + j][lr]; o1.s[j] = t[lc + 8 + j][lr]; }
  *reinterpret_cast<uint4*>(dp)     = o0.v;
  *reinterpret_cast<uint4*>(dp + 8) = o1.v;
}

// ================= bf16 transpose (for V^T) =================
__global__ __launch_bounds__(256) void trans_b(
    const unsigned short* __restrict__ src, unsigned short* __restrict__ dst,
    int sld, int dld, long long sbs, long long dbs, int scol)
{
  __shared__ unsigned short t[64][80];
  const int c0 = blockIdx.x * 64, r0 = blockIdx.y * 64;
  const int tid = threadIdx.x;
  const int lr = tid >> 2, lc = (tid & 3) * 16;

  const unsigned short* s = src + (size_t)sbs * blockIdx.z + (size_t)(r0 + lr) * sld + scol + c0 + lc;
  *reinterpret_cast<uint4*>(&t[lr][lc])     = *reinterpret_cast<const uint4*>(s);
  *reinterpret_cast<uint4*>(&t[lr][lc + 8]) = *reinterpret_cast<const uint4*>(s + 8);
  __syncthreads();

  unsigned short* dp = dst + (size_t)dbs * blockIdx.z + (size_t)(c0 + lr) * dld + r0 + lc;
  U8 o0, o1;
  #pragma unroll
  for (int j = 0; j < 8; ++j) { o0.s[j] = t[lc + j][lr]; o1.s[j] = t[lc + 8 + j][lr]; }
  *reinterpret_cast<uint4*>(dp)     = o0.v;
  *reinterpret_cast<uint4*>(dp + 8) = o1.v;
}

// ================= fp32 -> bf16 bulk convert =================
__global__ __launch_bounds__(256) void cvt_kernel(const float* __restrict__ in,
                                                  unsigned short* __restrict__ out, int n4)
{
  int i = blockIdx.x * 256 + threadIdx.x;
  if (i < n4) {
    const float4 v = reinterpret_cast<const float4*>(in)[i];
    ushort4 o; o.x = f2b(v.x); o.y = f2b(v.y); o.z = f2b(v.z); o.w = f2b(v.w);
    reinterpret_cast<ushort4*>(out)[i] = o;
  }
}

// ================= bias concat: bcat[3072] = {bq, bk, bv} =================
__global__ __launch_bounds__(1024) void bias3_k(
    const float* __restrict__ b0, const float* __restrict__ b1,
    const float* __restrict__ b2, float* __restrict__ out)
{
  const int z = blockIdx.x, tid = threadIdx.x;
  const float* s = (z == 0) ? b0 : (z == 1) ? b1 : b2;
  out[z * 1024 + tid] = s[tid];
}

// ================= causal row softmax (fp32 in place, optional bf16 dual write) ======
template<int DUAL>
__global__ __launch_bounds__(256) void softmax_f32(float* __restrict__ w,
                                                   unsigned short* __restrict__ pb)
{
  const int S = 2048;
  const int gr = blockIdx.x;          // b*S + q
  const int q = gr & (S - 1);
  float* row = w + (size_t)gr * S;
  const int valid = q + 1;
  const int tid = threadIdx.x, lane = tid & 63, wv = tid >> 6;
  __shared__ float red[8];

  const int e0 = tid * 4, e1 = (tid + 256) * 4;
  float4 v0 = make_float4(0.f, 0.f, 0.f, 0.f), v1 = v0;
  if (e0 < valid) v0 = reinterpret_cast<const float4*>(row)[tid];        // causal read-skip
  if (e1 < valid) v1 = reinterpret_cast<const float4*>(row)[tid + 256];
  float a[8] = { v0.x, v0.y, v0.z, v0.w, v1.x, v1.y, v1.z, v1.w };
  const int idx[8] = { e0, e0+1, e0+2, e0+3, e1, e1+1, e1+2, e1+3 };

  float m = -3.0e38f;
  #pragma unroll
  for (int j = 0; j < 8; ++j) if (idx[j] < valid) m = fmaxf(m, a[j]);
  #pragma unroll
  for (int o = 32; o; o >>= 1) m = fmaxf(m, __shfl_down(m, o, 64));
  if (lane == 0) red[wv] = m;
  __syncthreads();
  m = fmaxf(fmaxf(red[0], red[1]), fmaxf(red[2], red[3]));

  float s = 0.f;
  #pragma unroll
  for (int j = 0; j < 8; ++j) {
    a[j] = (idx[j] < valid) ? __expf(a[j] - m) : 0.f;
    s += a[j];
  }
  #pragma unroll
  for (int o = 32; o; o >>= 1) s += __shfl_down(s, o, 64);
  if (lane == 0) red[4 + wv] = s;
  __syncthreads();
  s = red[4] + red[5] + red[6] + red[7];
  const float inv = 1.f / s;

  #pragma unroll
  for (int j = 0; j < 8; ++j) a[j] *= inv;
  reinterpret_cast<float4*>(row)[tid]       = make_float4(a[0], a[1], a[2], a[3]);
  reinterpret_cast<float4*>(row)[tid + 256] = make_float4(a[4], a[5], a[6], a[7]);
  if (DUAL) {
    // PV reads K-blocks of 128 up to ceil(valid/128); beyond that Pb is never read.
    const int plim = ((q >> 7) + 1) << 7;
    unsigned short* pr = pb + (size_t)gr * S;
    if (e0 < plim) {
      ushort4 p0;
      p0.x = f2b(a[0]); p0.y = f2b(a[1]); p0.z = f2b(a[2]); p0.w = f2b(a[3]);
      reinterpret_cast<ushort4*>(pr)[tid] = p0;
    }
    if (e1 < plim) {
      ushort4 p1;
      p1.x = f2b(a[4]); p1.y = f2b(a[5]); p1.z = f2b(a[6]); p1.w = f2b(a[7]);
      reinterpret_cast<ushort4*>(pr)[tid + 256] = p1;
    }
  }
}

// ================= residual + LayerNorm =================
DEV float blockSum(float v, float* red) {
  #pragma unroll
  for (int o = 32; o; o >>= 1) v += __shfl_down(v, o, 64);
  const int lane = threadIdx.x & 63, wv = threadIdx.x >> 6;
  if (lane == 0) red[wv] = v;
  __syncthreads();
  float r = red[0] + red[1] + red[2] + red[3];
  __syncthreads();
  return r;
}

template<int AF32, int OF32>
__global__ __launch_bounds__(256) void ln_k(
    const void* __restrict__ xav, const unsigned short* __restrict__ xb,
    const float* __restrict__ g, const float* __restrict__ be,
    void* __restrict__ outv)
{
  const int D = 1024;
  const int r = blockIdx.x, tid = threadIdx.x;
  float a0, a1, a2, a3;
  if (AF32) {
    const float4 va = reinterpret_cast<const float4*>((const float*)xav + (size_t)r * D)[tid];
    a0 = va.x; a1 = va.y; a2 = va.z; a3 = va.w;
  } else {
    const ushort4 va = reinterpret_cast<const ushort4*>((const unsigned short*)xav + (size_t)r * D)[tid];
    a0 = b2f(va.x); a1 = b2f(va.y); a2 = b2f(va.z); a3 = b2f(va.w);
  }
  const ushort4 vb = reinterpret_cast<const ushort4*>(xb + (size_t)r * D)[tid];
  const float x0 = a0 + b2f(vb.x), x1 = a1 + b2f(vb.y);
  const float x2 = a2 + b2f(vb.z), x3 = a3 + b2f(vb.w);
  __shared__ float red[4];
  const float S1 = blockSum(x0 + x1 + x2 + x3, red);
  const float S2 = blockSum(x0*x0 + x1*x1 + x2*x2 + x3*x3, red);
  const float mu  = S1 * (1.f / 1024.f);
  const float var = S2 * (1.f / 1024.f) - mu * mu;
  const float rs  = rsqrtf(var + 1e-5f);
  const float4 gv = reinterpret_cast<const float4*>(g)[tid];
  const float4 bv = reinterpret_cast<const float4*>(be)[tid];
  const float o0 = (x0 - mu) * rs * gv.x + bv.x;
  const float o1 = (x1 - mu) * rs * gv.y + bv.y;
  const float o2 = (x2 - mu) * rs * gv.z + bv.z;
  const float o3 = (x3 - mu) * rs * gv.w + bv.w;
  if (OF32) {
    reinterpret_cast<float4*>((float*)outv + (size_t)r * D)[tid] = make_float4(o0, o1, o2, o3);
  } else {
    ushort4 ob; ob.x = f2b(o0); ob.y = f2b(o1); ob.z = f2b(o2); ob.w = f2b(o3);
    reinterpret_cast<ushort4*>((unsigned short*)outv + (size_t)r * D)[tid] = ob;
  }
}

// ================= fallback reg-staged GEMM (round-3, for small ws) =================
template<int TB, int AF32, int BF32, int BIAS, int RELU, int OF32, int CSKIP, int CKLIM>
__global__ __launch_bounds__(256) void gemm_rs(
    const void* __restrict__ Av, const void* __restrict__ Bv,
    const float* __restrict__ bias, void* __restrict__ outv,
    int K, int lda, int ldb, int ldc,
    long long bsA, long long bsB, long long bsC, float scale)
{
  const int n0 = blockIdx.x * 128, m0 = blockIdx.y * 128;
  if (CSKIP && n0 > m0 + 127) return;
  const size_t zA = (size_t)bsA * blockIdx.z;
  const size_t zB = (size_t)bsB * blockIdx.z;
  const float*          Afp = (const float*)Av;
  const unsigned short* Abf = (const unsigned short*)Av;
  const float*          Bfp = (const float*)Bv;
  const unsigned short* Bbf = (const unsigned short*)Bv;

  __shared__ unsigned short As[128][40];
  __shared__ unsigned short Bs[128][40];

  const int tid  = threadIdx.x;
  const int lane = tid & 63, wid = tid >> 6;
  const int wm = (wid >> 1) * 64, wn = (wid & 1) * 64;
  const int fr = lane & 15, kc = (lane >> 4) * 8;

  f32x4 acc[4][4] = {};
  int ktEnd = K >> 5;
  if (CKLIM) { int lim = (m0 + 128) >> 5; if (lim < ktEnd) ktEnd = lim; }

  for (int kt = 0; kt < ktEnd; ++kt) {
    __syncthreads();
    #pragma unroll
    for (int i = 0; i < 2; ++i) {
      const int ff = tid + i * 256;
      const int r = ff >> 2, c8 = (ff & 3) * 8;
      const size_t off = zA + (size_t)(m0 + r) * lda + kt * 32 + c8;
      U8 u;
      if (AF32) {
        const float4 v0 = *reinterpret_cast<const float4*>(Afp + off);
        const float4 v1 = *reinterpret_cast<const float4*>(Afp + off + 4);
        u.s[0]=f2b(v0.x); u.s[1]=f2b(v0.y); u.s[2]=f2b(v0.z); u.s[3]=f2b(v0.w);
        u.s[4]=f2b(v1.x); u.s[5]=f2b(v1.y); u.s[6]=f2b(v1.z); u.s[7]=f2b(v1.w);
      } else u.v = *reinterpret_cast<const uint4*>(Abf + off);
      *reinterpret_cast<uint4*>(&As[r][c8]) = u.v;
    }
    if (TB) {
      #pragma unroll
      for (int i = 0; i < 2; ++i) {
        const int ff = tid + i * 256;
        const int r = ff >> 2, c8 = (ff & 3) * 8;
        const size_t off = zB + (size_t)(n0 + r) * ldb + kt * 32 + c8;
        U8 u;
        if (BF32) {
          const float4 v0 = *reinterpret_cast<const float4*>(Bfp + off);
          const float4 v1 = *reinterpret_cast<const float4*>(Bfp + off + 4);
          u.s[0]=f2b(v0.x); u.s[1]=f2b(v0.y); u.s[2]=f2b(v0.z); u.s[3]=f2b(v0.w);
          u.s[4]=f2b(v1.x); u.s[5]=f2b(v1.y); u.s[6]=f2b(v1.z); u.s[7]=f2b(v1.w);
        } else u.v = *reinterpret_cast<const uint4*>(Bbf + off);
        *reinterpret_cast<uint4*>(&Bs[r][c8]) = u.v;
      }
    } else {
      #pragma unroll
      for (int i = 0; i < 2; ++i) {
        const int ff = tid + i * 256;
        const int k = ff >> 4, c8 = (ff & 15) * 8;
        const size_t off = zB + (size_t)(kt * 32 + k) * ldb + n0 + c8;
        U8 u;
        if (BF32) {
          const float4 v0 = *reinterpret_cast<const float4*>(Bfp + off);
          const float4 v1 = *reinterpret_cast<const float4*>(Bfp + off + 4);
          u.s[0]=f2b(v0.x); u.s[1]=f2b(v0.y); u.s[2]=f2b(v0.z); u.s[3]=f2b(v0.w);
          u.s[4]=f2b(v1.x); u.s[5]=f2b(v1.y); u.s[6]=f2b(v1.z); u.s[7]=f2b(v1.w);
        } else u.v = *reinterpret_cast<const uint4*>(Bbf + off);
        #pragma unroll
        for (int j = 0; j < 8; ++j) Bs[c8 + j][k] = u.s[j];
      }
    }
    __syncthreads();

    short8 af[4], bfr[4];
    #pragma unroll
    for (int i = 0; i < 4; ++i) af[i]  = *reinterpret_cast<const short8*>(&As[wm + i * 16 + fr][kc]);
    #pragma unroll
    for (int i = 0; i < 4; ++i) bfr[i] = *reinterpret_cast<const short8*>(&Bs[wn + i * 16 + fr][kc]);
    #pragma unroll
    for (int mi = 0; mi < 4; ++mi)
      #pragma unroll
      for (int ni = 0; ni < 4; ++ni)
        acc[mi][ni] = __builtin_amdgcn_mfma_f32_16x16x32_bf16(af[mi], bfr[ni], acc[mi][ni], 0, 0, 0);
  }

  const int cc = lane & 15, r4 = (lane >> 4) * 4;
  const size_t cb = (size_t)bsC * blockIdx.z;
  float*          outF = (float*)outv;
  unsigned short* outB = (unsigned short*)outv;
  #pragma unroll
  for (int mi = 0; mi < 4; ++mi) {
    #pragma unroll
    for (int ni = 0; ni < 4; ++ni) {
      const int col = n0 + wn + ni * 16 + cc;
      const float bv = BIAS ? bias[col] : 0.f;
      #pragma unroll
      for (int j = 0; j < 4; ++j) {
        const int row = m0 + wm + mi * 16 + r4 + j;
        float v = acc[mi][ni][j] * scale + bv;
        if (RELU) v = fmaxf(v, 0.f);
        if (OF32) outF[cb + (size_t)row * ldc + col] = v;
        else      outB[cb + (size_t)row * ldc + col] = f2b(v);
      }
    }
  }
}

// ================= launch =================
extern "C" void kernel_launch(void* const* d_in, const int* in_sizes, int n_in,
                              void* d_out, int out_size, void* d_ws, size_t ws_size,
                              hipStream_t stream)
{
  (void)in_sizes; (void)n_in; (void)out_size;
  const int B = 4, S = 2048, D = 1024;
  const int M = B * S;
  const long long SD = (long long)S * D, SS = (long long)S * S;
  const size_t MB = 1024 * 1024;

  const float* x   = (const float*)d_in[0];
  const float* Wq  = (const float*)d_in[1];  const float* bq  = (const float*)d_in[2];
  const float* Wk  = (const float*)d_in[3];  const float* bk  = (const float*)d_in[4];
  const float* Wv  = (const float*)d_in[5];  const float* bv  = (const float*)d_in[6];
  const float* W1  = (const float*)d_in[7];  const float* b1  = (const float*)d_in[8];
  const float* W2  = (const float*)d_in[9];  const float* b2  = (const float*)d_in[10];
  const float* g1  = (const float*)d_in[11]; const float* be1 = (const float*)d_in[12];
  const float* g2  = (const float*)d_in[13]; const float* be2 = (const float*)d_in[14];

  float* out0f = (float*)d_out;                 // [B,S,D] fp32 (written by final LN)
  float* woutf = out0f + (size_t)M * D;         // [B,S,S] fp32 weights

  if (ws_size >= 112 * MB + 16384) {
    // ---------- tier A: all-bf16 GLL pipeline ----------
    char* ws = (char*)d_ws;
    unsigned short* xb   = (unsigned short*)(ws);            // [0,16M) -> h after QKV
    unsigned short* QKVb = (unsigned short*)(ws + 16 * MB);  // [16M,64M) [8192,3072]
    unsigned short* VT   = (unsigned short*)(ws + 64 * MB);  // [64M,80M) [B,1024,2048]
    unsigned short* Pb   = (unsigned short*)(ws + 80 * MB);  // [80M,112M) [B,S,S]
    float*          bcat = (float*)(ws + 112 * MB);          // [3072]
    unsigned short* h    = xb;                               // reuse (xb dead after QKV)
    unsigned short* attn = QKVb;                             // reuse Q region
    unsigned short* f2   = QKVb + 8 * MB;                    // reuse K region (u16: +16MB)

    unsigned short* outu = (unsigned short*)d_out;           // out0 region (dead till LN2)
    unsigned short* WqkvT = outu;                            // [3072][1024] bf16, 6 MB
    unsigned short* W1T   = outu + 3072 * 1024;              // 2 MB
    unsigned short* W2T   = outu + 4096 * 1024;              // 2 MB
    unsigned short* f1    = outu + 8 * MB;                   // [16MB,32MB) of out0

    // 1. convert / transpose operands (batched)
    cvt_kernel<<<M * D / 4 / 256, 256, 0, stream>>>(x, xb, M * D / 4);
    bias3_k<<<3, 1024, 0, stream>>>(bq, bk, bv, bcat);
    wtrans5<<<dim3(16, 16, 5), 256, 0, stream>>>(Wq, Wk, Wv, W1, W2, WqkvT);

    // 2. merged QKV projection: [8192,3072]  (scale==1 -> SCALED=0)
    gemm_gll<1,0,0,0,0,0><<<dim3(24, 64, 1), 256, 0, stream>>>(xb, WqkvT, bcat, QKVb,
        D, D, D, 3072, 0, 0, 0, 1.f);

    // 3. V^T per batch: [1024,2048]
    trans_b<<<dim3(16, 32, 4), 256, 0, stream>>>(QKVb, VT, 3072, 2048,
        2048LL * 3072, 1024LL * 2048, 2048);

    // 4. scores = Q K^T / 32 -> fp32 weights (causal blocks skipped)
    gemm_gll<0,0,1,1,1,0><<<dim3(16, 16, 4), 256, 0, stream>>>(QKVb, QKVb + 1024, nullptr, woutf,
        D, 3072, 3072, S, 2048LL * 3072, 2048LL * 3072, SS, 1.f / 32.f);

    // 5. softmax in place + bf16 dual write (skip P-writes beyond diag block)
    softmax_f32<1><<<B * S, 256, 0, stream>>>(woutf, Pb);

    // 6. attn = P V  (A=Pb bf16, B=VT, K clipped) -> attn bf16
    gemm_gll<0,0,0,0,0,1><<<dim3(8, 16, 4), 256, 0, stream>>>(Pb, VT, nullptr, attn,
        S, S, S, D, SS, (long long)D * S, SD, 1.f);

    // 7. h = LN(x + attn)
    ln_k<1,0><<<M, 256, 0, stream>>>(x, attn, g1, be1, h);

    // 8. f1 = relu(h W1T^T + b1)
    gemm_gll<1,1,0,0,0,0><<<dim3(8, 64, 1), 256, 0, stream>>>(h, W1T, b1, f1,
        D, D, D, D, 0, 0, 0, 1.f);

    // 9. f2 = f1 W2T^T + b2
    gemm_gll<1,0,0,0,0,0><<<dim3(8, 64, 1), 256, 0, stream>>>(f1, W2T, b2, f2,
        D, D, D, D, 0, 0, 0, 1.f);

    // 10. out = LN(h + f2) -> fp32
    ln_k<0,1><<<M, 256, 0, stream>>>(h, f2, g2, be2, out0f);
  } else {
    // ---------- tier C: round-3 fallback (32 MB ws) ----------
    unsigned short* slot0 = (unsigned short*)d_ws;
    unsigned short* slot1 = (unsigned short*)((char*)d_ws + (size_t)M * D * 2);
    unsigned short* Vb  = (unsigned short*)d_out;
    unsigned short* f1b = (unsigned short*)d_out;

    dim3 gProj(D / 128, M / 128, 1);
    dim3 gSc(S / 128, S / 128, B);
    dim3 gPV(D / 128, S / 128, B);

    gemm_rs<0,1,1,1,0,0,0,0><<<gProj, 256, 0, stream>>>(x, Wq, bq, slot0, D, D, D, D, 0, 0, 0, 1.f);
    gemm_rs<0,1,1,1,0,0,0,0><<<gProj, 256, 0, stream>>>(x, Wk, bk, slot1, D, D, D, D, 0, 0, 0, 1.f);
    gemm_rs<0,1,1,1,0,0,0,0><<<gProj, 256, 0, stream>>>(x, Wv, bv, Vb,    D, D, D, D, 0, 0, 0, 1.f);
    gemm_rs<1,0,0,0,0,1,1,0><<<gSc, 256, 0, stream>>>(slot0, slot1, nullptr, woutf,
        D, D, D, S, SD, SD, SS, 1.f / 32.f);
    softmax_f32<0><<<B * S, 256, 0, stream>>>(woutf, nullptr);
    gemm_rs<0,1,0,0,0,0,0,1><<<gPV, 256, 0, stream>>>(woutf, Vb, nullptr, slot0,
        S, S, D, D, SS, SD, SD, 1.f);
    ln_k<1,0><<<M, 256, 0, stream>>>(x, slot0, g1, be1, slot1);
    gemm_rs<0,0,1,1,1,0,0,0><<<gProj, 256, 0, stream>>>(slot1, W1, b1, f1b, D, D, D, D, 0, 0, 0, 1.f);
    gemm_rs<0,0,1,1,0,0,0,0><<<gProj, 256, 0, stream>>>(f1b, W2, b2, slot0, D, D, D, D, 0, 0, 0, 1.f);
    ln_k<0,1><<<M, 256, 0, stream>>>(slot1, slot0, g2, be2, out0f);
  }
}